// Round 13
// baseline (570.891 us; speedup 1.0000x reference)
//
#include <hip/hip_runtime.h>
#include <math.h>

#define BB 8
#define NN 64
#define SS 128
#define DD 512
#define HH 8
#define DKK 64
#define NSENT (BB * NN)          // 512
#define SENT_STRIDE (SS * DD)    // 65536 floats per sentence of x / out
#define NTILE 16                 // 16 tiles x 8 tokens

// d_ws layout (floats)
#define WK_OFF 0                          // wk_t[8][512]        (16 KB)
#define XB_OFF 4096                       // xbar[512][8][512]   (8 MB)
#define Z_OFF  (XB_OFF + NSENT * HH * DD) // z[512][512]         (1 MB)
#define YY_OFF (Z_OFF + NSENT * DD)       // y[512][512]         (1 MB)

#define GLOBAL_AS(p) ((const __attribute__((address_space(1))) void*)(p))
#define LDS_AS(p)    ((__attribute__((address_space(3))) void*)(p))

// ---------------------------------------------------------------------------
// K0: fold Wk with sent_q: wk_t[h][d] = sum_k Wk[d, h*64+k] * sent_q[h,k]
// (bk is softmax-shift-invariant; Wq/bq dead: token softmax is over a singleton)
// ---------------------------------------------------------------------------
__global__ void precompute_wk(const float* __restrict__ Wk,
                              const float* __restrict__ sq,
                              float* __restrict__ wk_t) {
    const int d = threadIdx.x;
    const int h = blockIdx.x;
    const float4* wrow = (const float4*)(Wk + (size_t)d * DD + h * DKK);
    const float4* sqv  = (const float4*)(sq + h * DKK);
    float acc = 0.f;
#pragma unroll
    for (int k = 0; k < DKK / 4; ++k) {
        float4 w = wrow[k], q = sqv[k];
        acc += w.x * q.x + w.y * q.y + w.z * q.z + w.w * q.w;
    }
    wk_t[h * DD + d] = acc;
}

// ---------------------------------------------------------------------------
// KA-LDS: single HBM pass over x via global_load_lds, 4-buffer x 8-token
// tiles, depth-3 prefetch with counted vmcnt (never drained in-loop).
// Block = sentence, 512 thr (8 waves).
//  dots:  wave w owns token row w of the tile; lane dims strided (lane+64k,
//         2-way bank-free); wk in 64 VGPRs; 6-level xor reduce; e -> wl.
//  accum: thread t owns dim t; acc[h] += wl[tok][h] * xt[tok][t] from LDS.
// End: per-head wsum from wl, normalize, write xbar.
// ---------------------------------------------------------------------------
__global__ __launch_bounds__(512, 4)
void ka_lds(const float* __restrict__ x, const int* __restrict__ mask,
            const float* __restrict__ wk_t, float* __restrict__ xbar)
{
    __shared__ float xt[4][8][DD];   // 64 KB
    __shared__ float wl[SS][HH];     // 4 KB
    __shared__ int   ml[SS];         // 512 B
    __shared__ float rsh[HH];

    const int sent = blockIdx.x;
    const int t    = threadIdx.x;
    const int wave = t >> 6;
    const int lane = t & 63;
    const float* xs = x + (size_t)sent * SENT_STRIDE;

    // wk strided fragments: wkr[h][k] = wk_t[h][lane + 64k]  (64 VGPRs,
    // coalesced 256B loads, L2-hot after first blocks)
    float wkr[HH][8];
#pragma unroll
    for (int h = 0; h < HH; ++h)
#pragma unroll
        for (int k = 0; k < 8; ++k)
            wkr[h][k] = wk_t[h * DD + lane + 64 * k];

    int mreg = 0;
    if (t < SS) mreg = mask[sent * SS + t];
    // drain wk+mask so the loop's counted vmcnt sees only stage loads
    asm volatile("s_waitcnt vmcnt(0)" ::: "memory");
    if (t < SS) ml[t] = mreg;
    asm volatile("s_waitcnt lgkmcnt(0)" ::: "memory");

    float acc[HH];
#pragma unroll
    for (int h = 0; h < HH; ++h) acc[h] = 0.f;

    // stage tile (16KB): wave w covers floats [w*512, w*512+512) via 2 calls
    // (LDS dest wave-uniform base, lane*16B implicit; linear layout)
#define STAGE(buf_i, tile_i)                                                    \
    do {                                                                        \
        const float* g0 = xs + (tile_i) * (8 * DD) + wave * 512 + lane * 4;     \
        float* l0 = &xt[(buf_i)][0][0] + wave * 512;                            \
        __builtin_amdgcn_global_load_lds(GLOBAL_AS(g0), LDS_AS(l0), 16, 0, 0);  \
        __builtin_amdgcn_global_load_lds(GLOBAL_AS(g0 + 256), LDS_AS(l0 + 256), 16, 0, 0); \
    } while (0)

    STAGE(0, 0);
    STAGE(1, 1);
    STAGE(2, 2);

#pragma unroll
    for (int tile = 0; tile < NTILE; ++tile) {
        // wait: tile's 2 loads done (outstanding after: newer stages only)
        if (tile <= 13)      asm volatile("s_waitcnt vmcnt(4)" ::: "memory");
        else if (tile == 14) asm volatile("s_waitcnt vmcnt(2)" ::: "memory");
        else                 asm volatile("s_waitcnt vmcnt(0)" ::: "memory");
        __builtin_amdgcn_s_barrier();          // all waves done with accum(tile-1)
        __builtin_amdgcn_sched_barrier(0);
        if (tile + 3 < NTILE) STAGE((tile + 3) & 3, tile + 3);  // refill freed buf

        const int buf = tile & 3;

        // ---- dots: wave w = token row w ----
        {
            float xv[8];
#pragma unroll
            for (int k = 0; k < 8; ++k) xv[k] = xt[buf][wave][lane + 64 * k];
            float p[HH];
#pragma unroll
            for (int h = 0; h < HH; ++h) {
                float s0 = xv[0] * wkr[h][0] + xv[1] * wkr[h][1]
                         + xv[2] * wkr[h][2] + xv[3] * wkr[h][3];
                float s1 = xv[4] * wkr[h][4] + xv[5] * wkr[h][5]
                         + xv[6] * wkr[h][6] + xv[7] * wkr[h][7];
                p[h] = s0 + s1;
            }
#pragma unroll
            for (int off = 1; off <= 4; off <<= 1)
#pragma unroll
                for (int h = 0; h < HH; ++h)
                    p[h] += __shfl_xor(p[h], off, 64);
            const int r = lane & 7;
            float v = p[0];
#pragma unroll
            for (int h = 1; h < HH; ++h) v = (r == h) ? p[h] : v;
            v += __shfl_xor(v, 8, 64);
            v += __shfl_xor(v, 16, 64);
            v += __shfl_xor(v, 32, 64);
            const int tok = tile * 8 + wave;
            const float e = ml[tok] ? __expf(v * 0.125f) : 0.f;
            if (lane < HH) wl[tok][lane] = e;   // lane i holds head i's value
        }
        asm volatile("s_waitcnt lgkmcnt(0)" ::: "memory");
        __builtin_amdgcn_s_barrier();          // wl visible; prefetch stays in flight
        __builtin_amdgcn_sched_barrier(0);

        // ---- accum: thread t owns dim t ----
#pragma unroll
        for (int j = 0; j < 8; ++j) {
            const float xv = xt[buf][j][t];
            const float4 w0 = *(const float4*)&wl[tile * 8 + j][0];
            const float4 w1 = *(const float4*)&wl[tile * 8 + j][4];
            acc[0] += w0.x * xv; acc[1] += w0.y * xv;
            acc[2] += w0.z * xv; acc[3] += w0.w * xv;
            acc[4] += w1.x * xv; acc[5] += w1.y * xv;
            acc[6] += w1.z * xv; acc[7] += w1.w * xv;
        }
    }
#undef STAGE

    // ---- per-head wsum: wave w reduces wl[:][w] ----
    {
        float v = wl[lane][wave] + wl[lane + 64][wave];
#pragma unroll
        for (int off = 1; off <= 32; off <<= 1)
            v += __shfl_xor(v, off, 64);
        if (lane == 0) rsh[wave] = 1.0f / v;
    }
    asm volatile("s_waitcnt lgkmcnt(0)" ::: "memory");
    __builtin_amdgcn_s_barrier();

    float* xbp = xbar + (size_t)sent * (HH * DD) + t;
#pragma unroll
    for (int h = 0; h < HH; ++h)
        xbp[h * DD] = acc[h] * rsh[h];
}

// ---------------------------------------------------------------------------
// KZ/KY: 16x64-tile fp32 GEMM, register-prefetched across the barrier,
// 256 blocks (proven R8/R11).
//  KZ: A=xbar (am=4096, a_nb=512 head select), B=Wv, bias=bv -> z
//  KY: A=z    (am=512,  a_nb=0),               B=Wo, bias=bo -> y
// ---------------------------------------------------------------------------
__global__ __launch_bounds__(256)
void gemm_tile(const float* __restrict__ A, const int am_stride, const int a_nb_stride,
               const float* __restrict__ B, const float* __restrict__ bias,
               float* __restrict__ C)
{
    __shared__ float As[64][17];   // [k][m]
    __shared__ float Bs[64][68];   // [k][n]

    const int nb = blockIdx.x & 7, mb = blockIdx.x >> 3;
    const int t  = threadIdx.x;
    const int tr = t >> 4, tc = t & 15;

    const float* Ab = A + (size_t)(mb * 16) * am_stride + nb * a_nb_stride
                        + (size_t)tr * am_stride + tc * 4;
    const float* Bb = B + nb * 64 + (size_t)tr * DD + tc * 4;

    float4 ar = *(const float4*)(Ab);
    float4 br0 = *(const float4*)(Bb);
    float4 br1 = *(const float4*)(Bb + 16 * DD);
    float4 br2 = *(const float4*)(Bb + 32 * DD);
    float4 br3 = *(const float4*)(Bb + 48 * DD);

    float a0 = 0.f, a1 = 0.f, a2 = 0.f, a3 = 0.f;

    for (int k0 = 0; k0 < DD; k0 += 64) {
        As[tc * 4 + 0][tr] = ar.x;
        As[tc * 4 + 1][tr] = ar.y;
        As[tc * 4 + 2][tr] = ar.z;
        As[tc * 4 + 3][tr] = ar.w;
        *(float4*)&Bs[tr +  0][tc * 4] = br0;
        *(float4*)&Bs[tr + 16][tc * 4] = br1;
        *(float4*)&Bs[tr + 32][tc * 4] = br2;
        *(float4*)&Bs[tr + 48][tc * 4] = br3;
        __syncthreads();
        if (k0 + 64 < DD) {       // prefetch next K-tile; overlaps compute below
            ar  = *(const float4*)(Ab + k0 + 64);
            br0 = *(const float4*)(Bb + (size_t)(k0 + 64) * DD);
            br1 = *(const float4*)(Bb + (size_t)(k0 + 80) * DD);
            br2 = *(const float4*)(Bb + (size_t)(k0 + 96) * DD);
            br3 = *(const float4*)(Bb + (size_t)(k0 + 112) * DD);
        }
#pragma unroll
        for (int kk = 0; kk < 64; ++kk) {
            const float av = As[kk][tr];
            const float4 bv4 = *(const float4*)&Bs[kk][tc * 4];
            a0 += av * bv4.x; a1 += av * bv4.y; a2 += av * bv4.z; a3 += av * bv4.w;
        }
        __syncthreads();
    }

    const float4 bb = *(const float4*)(bias + nb * 64 + tc * 4);
    float4 o; o.x = a0 + bb.x; o.y = a1 + bb.y; o.z = a2 + bb.z; o.w = a3 + bb.w;
    *(float4*)(C + (size_t)(mb * 16 + tr) * DD + nb * 64 + tc * 4) = o;
}

// ---------------------------------------------------------------------------
// KB: broadcast y[sent] to all 128 token rows of out. 2048 blocks x 256 thr.
// Wave-stores are 1KB contiguous (proven-fast write pattern).
// ---------------------------------------------------------------------------
__global__ __launch_bounds__(256)
void kb_bcast(const float* __restrict__ y, float* __restrict__ outp)
{
    const int sent = blockIdx.x >> 2, q = blockIdx.x & 3;
    const int c4 = threadIdx.x & 127;       // float4 column 0..127
    const int rr = threadIdx.x >> 7;        // 0..1
    const float4 yv = *(const float4*)(y + (size_t)sent * DD + c4 * 4);
    float* w0 = outp + (size_t)sent * SENT_STRIDE + (size_t)(q * 32 + rr) * DD + c4 * 4;
#pragma unroll
    for (int i = 0; i < 16; ++i)
        *(float4*)(w0 + (size_t)(i * 2) * DD) = yv;
}

extern "C" void kernel_launch(void* const* d_in, const int* in_sizes, int n_in,
                              void* d_out, int out_size, void* d_ws, size_t ws_size,
                              hipStream_t stream) {
    const float* x    = (const float*)d_in[0];
    const int*   mask = (const int*)  d_in[1];
    // d_in[2]=Wq, d_in[3]=bq dead (token softmax over singleton); d_in[5]=bk shift-invariant
    const float* Wk   = (const float*)d_in[4];
    const float* Wv   = (const float*)d_in[6];
    const float* bv   = (const float*)d_in[7];
    const float* sq   = (const float*)d_in[8];
    const float* Wo   = (const float*)d_in[9];
    const float* bo   = (const float*)d_in[10];
    float* out = (float*)d_out;
    float* ws  = (float*)d_ws;

    float* wk_t = ws + WK_OFF;
    float* xbar = ws + XB_OFF;
    float* z    = ws + Z_OFF;
    float* y    = ws + YY_OFF;

    precompute_wk<<<HH, DD, 0, stream>>>(Wk, sq, wk_t);
    ka_lds<<<NSENT, 512, 0, stream>>>(x, mask, wk_t, xbar);
    gemm_tile<<<256, 256, 0, stream>>>(xbar, HH * DD, DD, Wv, bv, z);
    gemm_tile<<<256, 256, 0, stream>>>(z, DD, 0, Wo, bo, y);
    kb_bcast<<<NSENT * 4, 256, 0, stream>>>(y, out);
}

// Round 14
// 127.152 us; speedup vs baseline: 4.4898x; 4.4898x over previous
//
#include <hip/hip_runtime.h>
#include <math.h>

#define BB 8
#define NN 64
#define SS 128
#define DD 512
#define HH 8
#define DKK 64
#define NSENT (BB * NN)          // 512
#define SENT_STRIDE (SS * DD)    // 65536 floats per sentence of x / out
#define NTILE 16                 // 16 tiles x 8 tokens

// d_ws layout (floats)
#define WK_OFF 0                          // wk_t[8][512]        (16 KB)
#define XB_OFF 4096                       // xbar[512][8][512]   (8 MB)
#define Z_OFF  (XB_OFF + NSENT * HH * DD) // z[512][512]         (1 MB)
#define YY_OFF (Z_OFF + NSENT * DD)       // y[512][512]         (1 MB)

#define GLOBAL_AS(p) ((const __attribute__((address_space(1))) void*)(p))
#define LDS_AS(p)    ((__attribute__((address_space(3))) void*)(p))

// ---------------------------------------------------------------------------
// K0: fold Wk with sent_q: wk_t[h][d] = sum_k Wk[d, h*64+k] * sent_q[h,k]
// (bk is softmax-shift-invariant; Wq/bq dead: token softmax is over a singleton)
// ---------------------------------------------------------------------------
__global__ void precompute_wk(const float* __restrict__ Wk,
                              const float* __restrict__ sq,
                              float* __restrict__ wk_t) {
    const int d = threadIdx.x;
    const int h = blockIdx.x;
    const float4* wrow = (const float4*)(Wk + (size_t)d * DD + h * DKK);
    const float4* sqv  = (const float4*)(sq + h * DKK);
    float acc = 0.f;
#pragma unroll
    for (int k = 0; k < DKK / 4; ++k) {
        float4 w = wrow[k], q = sqv[k];
        acc += w.x * q.x + w.y * q.y + w.z * q.z + w.w * q.w;
    }
    wk_t[h * DD + d] = acc;
}

// ---------------------------------------------------------------------------
// KA-LDS: single HBM pass over x via global_load_lds, 4-buffer x 8-token
// tiles, depth-3 prefetch with counted vmcnt (never drained in-loop).
// Block = sentence, 512 thr (8 waves). NO launch-bounds min-waves arg:
// R13's (512,4) forced a 64-VGPR cap and spilled wkr (the 571us disaster).
//  dots:  wave w owns token row w of the tile (reads only its own staged
//         chunk); wk in 64 VGPRs; 6-level xor reduce; e -> wl.
//  accum: thread t owns dim t; acc[h] += wl[tok][h] * xt[tok][t] from LDS.
// End: per-head wsum from wl, normalize, write xbar.
// ---------------------------------------------------------------------------
__global__ __launch_bounds__(512)
void ka_lds(const float* __restrict__ x, const int* __restrict__ mask,
            const float* __restrict__ wk_t, float* __restrict__ xbar)
{
    __shared__ float xt[4][8][DD];   // 64 KB
    __shared__ float wl[SS][HH];     // 4 KB
    __shared__ int   ml[SS];         // 512 B
    __shared__ float rsh[HH];

    const int sent = blockIdx.x;
    const int t    = threadIdx.x;
    const int wave = t >> 6;
    const int lane = t & 63;
    const float* xs = x + (size_t)sent * SENT_STRIDE;

    // wk strided fragments: wkr[h][k] = wk_t[h][lane + 64k]  (64 VGPRs,
    // coalesced 256B loads, L2-hot after first blocks)
    float wkr[HH][8];
#pragma unroll
    for (int h = 0; h < HH; ++h)
#pragma unroll
        for (int k = 0; k < 8; ++k)
            wkr[h][k] = wk_t[h * DD + lane + 64 * k];

    int mreg = 0;
    if (t < SS) mreg = mask[sent * SS + t];
    // drain wk+mask so the loop's counted vmcnt sees only stage loads
    asm volatile("s_waitcnt vmcnt(0)" ::: "memory");
    if (t < SS) ml[t] = mreg;
    asm volatile("s_waitcnt lgkmcnt(0)" ::: "memory");

    float acc[HH];
#pragma unroll
    for (int h = 0; h < HH; ++h) acc[h] = 0.f;

    // stage tile (16KB): wave w covers floats [w*512, w*512+512) via 2 calls
    // (LDS dest wave-uniform base, lane*16B implicit; linear layout)
#define STAGE(buf_i, tile_i)                                                    \
    do {                                                                        \
        const float* g0 = xs + (size_t)(tile_i) * (8 * DD) + wave * 512 + lane * 4; \
        float* l0 = &xt[(buf_i)][0][0] + (buf_i >= 0 ? 0 : 0) + wave * 512;     \
        __builtin_amdgcn_global_load_lds(GLOBAL_AS(g0), LDS_AS(l0), 16, 0, 0);  \
        __builtin_amdgcn_global_load_lds(GLOBAL_AS(g0 + 256), LDS_AS(l0 + 256), 16, 0, 0); \
    } while (0)

    STAGE(0, 0);
    STAGE(1, 1);
    STAGE(2, 2);

    // ---- one tile's compute (dots + accum), shared by main loop & peel ----
#define TILE_BODY(tile)                                                         \
    {                                                                           \
        const int buf = (tile) & 3;                                             \
        /* dots: wave w = token row w */                                        \
        float xv[8];                                                            \
        _Pragma("unroll")                                                       \
        for (int k = 0; k < 8; ++k) xv[k] = xt[buf][wave][lane + 64 * k];       \
        float p[HH];                                                            \
        _Pragma("unroll")                                                       \
        for (int h = 0; h < HH; ++h) {                                          \
            float s0 = xv[0] * wkr[h][0] + xv[1] * wkr[h][1]                    \
                     + xv[2] * wkr[h][2] + xv[3] * wkr[h][3];                   \
            float s1 = xv[4] * wkr[h][4] + xv[5] * wkr[h][5]                    \
                     + xv[6] * wkr[h][6] + xv[7] * wkr[h][7];                   \
            p[h] = s0 + s1;                                                     \
        }                                                                       \
        _Pragma("unroll")                                                       \
        for (int off = 1; off <= 4; off <<= 1) {                                \
            _Pragma("unroll")                                                   \
            for (int h = 0; h < HH; ++h)                                        \
                p[h] += __shfl_xor(p[h], off, 64);                              \
        }                                                                       \
        const int r = lane & 7;                                                 \
        float v = p[0];                                                         \
        _Pragma("unroll")                                                       \
        for (int h = 1; h < HH; ++h) v = (r == h) ? p[h] : v;                   \
        v += __shfl_xor(v, 8, 64);                                              \
        v += __shfl_xor(v, 16, 64);                                             \
        v += __shfl_xor(v, 32, 64);                                             \
        const int tok = (tile) * 8 + wave;                                      \
        const float e = ml[tok] ? __expf(v * 0.125f) : 0.f;                     \
        if (lane < HH) wl[tok][lane] = e;                                       \
        asm volatile("s_waitcnt lgkmcnt(0)" ::: "memory");                      \
        __builtin_amdgcn_s_barrier();   /* wl visible; prefetch in flight */    \
        __builtin_amdgcn_sched_barrier(0);                                      \
        /* accum: thread t owns dim t */                                        \
        _Pragma("unroll")                                                       \
        for (int j = 0; j < 8; ++j) {                                           \
            const float xv2 = xt[buf][j][t];                                    \
            const float4 w0 = *(const float4*)&wl[(tile) * 8 + j][0];           \
            const float4 w1 = *(const float4*)&wl[(tile) * 8 + j][4];           \
            acc[0] += w0.x * xv2; acc[1] += w0.y * xv2;                         \
            acc[2] += w0.z * xv2; acc[3] += w0.w * xv2;                         \
            acc[4] += w1.x * xv2; acc[5] += w1.y * xv2;                         \
            acc[6] += w1.z * xv2; acc[7] += w1.w * xv2;                         \
        }                                                                       \
    }

    // main loop: tiles 0..13, uniform vmcnt(4) (outstanding = 3 stages x 2)
#pragma unroll 1
    for (int tile = 0; tile < 14; ++tile) {
        asm volatile("s_waitcnt vmcnt(4)" ::: "memory");
        __builtin_amdgcn_s_barrier();          // all waves done with accum(tile-1)
        __builtin_amdgcn_sched_barrier(0);
        if (tile < 13) STAGE((tile + 3) & 3, tile + 3);   // refill freed buf
        TILE_BODY(tile);
    }
    // peel tile 14 (2 stages outstanding) and 15 (1 stage outstanding)
    asm volatile("s_waitcnt vmcnt(2)" ::: "memory");
    __builtin_amdgcn_s_barrier();
    __builtin_amdgcn_sched_barrier(0);
    TILE_BODY(14);
    asm volatile("s_waitcnt vmcnt(0)" ::: "memory");
    __builtin_amdgcn_s_barrier();
    __builtin_amdgcn_sched_barrier(0);
    TILE_BODY(15);
#undef TILE_BODY
#undef STAGE

    // ---- per-head wsum: wave w reduces wl[:][w] ----
    {
        float v = wl[lane][wave] + wl[lane + 64][wave];
#pragma unroll
        for (int off = 1; off <= 32; off <<= 1)
            v += __shfl_xor(v, off, 64);
        if (lane == 0) rsh[wave] = 1.0f / v;
    }
    asm volatile("s_waitcnt lgkmcnt(0)" ::: "memory");
    __builtin_amdgcn_s_barrier();

    float* xbp = xbar + (size_t)sent * (HH * DD) + t;
#pragma unroll
    for (int h = 0; h < HH; ++h)
        xbp[h * DD] = acc[h] * rsh[h];
}

// ---------------------------------------------------------------------------
// KZ/KY: 16x64-tile fp32 GEMM, register-prefetched across the barrier,
// 256 blocks (proven R8/R11).
//  KZ: A=xbar (am=4096, a_nb=512 head select), B=Wv, bias=bv -> z
//  KY: A=z    (am=512,  a_nb=0),               B=Wo, bias=bo -> y
// ---------------------------------------------------------------------------
__global__ __launch_bounds__(256)
void gemm_tile(const float* __restrict__ A, const int am_stride, const int a_nb_stride,
               const float* __restrict__ B, const float* __restrict__ bias,
               float* __restrict__ C)
{
    __shared__ float As[64][17];   // [k][m]
    __shared__ float Bs[64][68];   // [k][n]

    const int nb = blockIdx.x & 7, mb = blockIdx.x >> 3;
    const int t  = threadIdx.x;
    const int tr = t >> 4, tc = t & 15;

    const float* Ab = A + (size_t)(mb * 16) * am_stride + nb * a_nb_stride
                        + (size_t)tr * am_stride + tc * 4;
    const float* Bb = B + nb * 64 + (size_t)tr * DD + tc * 4;

    float4 ar = *(const float4*)(Ab);
    float4 br0 = *(const float4*)(Bb);
    float4 br1 = *(const float4*)(Bb + 16 * DD);
    float4 br2 = *(const float4*)(Bb + 32 * DD);
    float4 br3 = *(const float4*)(Bb + 48 * DD);

    float a0 = 0.f, a1 = 0.f, a2 = 0.f, a3 = 0.f;

    for (int k0 = 0; k0 < DD; k0 += 64) {
        As[tc * 4 + 0][tr] = ar.x;
        As[tc * 4 + 1][tr] = ar.y;
        As[tc * 4 + 2][tr] = ar.z;
        As[tc * 4 + 3][tr] = ar.w;
        *(float4*)&Bs[tr +  0][tc * 4] = br0;
        *(float4*)&Bs[tr + 16][tc * 4] = br1;
        *(float4*)&Bs[tr + 32][tc * 4] = br2;
        *(float4*)&Bs[tr + 48][tc * 4] = br3;
        __syncthreads();
        if (k0 + 64 < DD) {       // prefetch next K-tile; overlaps compute below
            ar  = *(const float4*)(Ab + k0 + 64);
            br0 = *(const float4*)(Bb + (size_t)(k0 + 64) * DD);
            br1 = *(const float4*)(Bb + (size_t)(k0 + 80) * DD);
            br2 = *(const float4*)(Bb + (size_t)(k0 + 96) * DD);
            br3 = *(const float4*)(Bb + (size_t)(k0 + 112) * DD);
        }
#pragma unroll
        for (int kk = 0; kk < 64; ++kk) {
            const float av = As[kk][tr];
            const float4 bv4 = *(const float4*)&Bs[kk][tc * 4];
            a0 += av * bv4.x; a1 += av * bv4.y; a2 += av * bv4.z; a3 += av * bv4.w;
        }
        __syncthreads();
    }

    const float4 bb = *(const float4*)(bias + nb * 64 + tc * 4);
    float4 o; o.x = a0 + bb.x; o.y = a1 + bb.y; o.z = a2 + bb.z; o.w = a3 + bb.w;
    *(float4*)(C + (size_t)(mb * 16 + tr) * DD + nb * 64 + tc * 4) = o;
}

// ---------------------------------------------------------------------------
// KB: broadcast y[sent] to all 128 token rows of out. 2048 blocks x 256 thr.
// Wave-stores are 1KB contiguous (proven-fast write pattern).
// ---------------------------------------------------------------------------
__global__ __launch_bounds__(256)
void kb_bcast(const float* __restrict__ y, float* __restrict__ outp)
{
    const int sent = blockIdx.x >> 2, q = blockIdx.x & 3;
    const int c4 = threadIdx.x & 127;       // float4 column 0..127
    const int rr = threadIdx.x >> 7;        // 0..1
    const float4 yv = *(const float4*)(y + (size_t)sent * DD + c4 * 4);
    float* w0 = outp + (size_t)sent * SENT_STRIDE + (size_t)(q * 32 + rr) * DD + c4 * 4;
#pragma unroll
    for (int i = 0; i < 16; ++i)
        *(float4*)(w0 + (size_t)(i * 2) * DD) = yv;
}

extern "C" void kernel_launch(void* const* d_in, const int* in_sizes, int n_in,
                              void* d_out, int out_size, void* d_ws, size_t ws_size,
                              hipStream_t stream) {
    const float* x    = (const float*)d_in[0];
    const int*   mask = (const int*)  d_in[1];
    // d_in[2]=Wq, d_in[3]=bq dead (token softmax over singleton); d_in[5]=bk shift-invariant
    const float* Wk   = (const float*)d_in[4];
    const float* Wv   = (const float*)d_in[6];
    const float* bv   = (const float*)d_in[7];
    const float* sq   = (const float*)d_in[8];
    const float* Wo   = (const float*)d_in[9];
    const float* bo   = (const float*)d_in[10];
    float* out = (float*)d_out;
    float* ws  = (float*)d_ws;

    float* wk_t = ws + WK_OFF;
    float* xbar = ws + XB_OFF;
    float* z    = ws + Z_OFF;
    float* y    = ws + YY_OFF;

    precompute_wk<<<HH, DD, 0, stream>>>(Wk, sq, wk_t);
    ka_lds<<<NSENT, 512, 0, stream>>>(x, mask, wk_t, xbar);
    gemm_tile<<<256, 256, 0, stream>>>(xbar, HH * DD, DD, Wv, bv, z);
    gemm_tile<<<256, 256, 0, stream>>>(z, DD, 0, Wo, bo, y);
    kb_bcast<<<NSENT * 4, 256, 0, stream>>>(y, out);
}

// Round 15
// 107.751 us; speedup vs baseline: 5.2983x; 1.1801x over previous
//
#include <hip/hip_runtime.h>
#include <math.h>

#define BB 8
#define NN 64
#define SS 128
#define DD 512
#define HH 8
#define DKK 64
#define NSENT (BB * NN)          // 512
#define NTOK  (NSENT * SS)       // 65536
#define SENT_STRIDE (SS * DD)    // 65536 floats per sentence of x / out

// d_ws layout (floats). z aliases w (w dead once kx finishes).
#define WK_OFF 0                          // wk_t[8][512]           (16 KB)
#define W_OFF  4096                       // w[65536][8]            (2 MB)
#define Z_OFF  4096                       // z[512][512]  (aliases w, 1 MB)
#define XB_OFF (W_OFF + NTOK * HH)        // xbar[512][8][512]      (8 MB)
#define YY_OFF (XB_OFF + NSENT * HH * DD) // y[512][512]            (1 MB)

// ---------------------------------------------------------------------------
// DPP helpers (imm operands must be ICE -> template params)
// ---------------------------------------------------------------------------
template <int CTRL>
__device__ __forceinline__ float ror_add(float v) {
    int r = __builtin_amdgcn_update_dpp(0, __float_as_int(v), CTRL, 0xf, 0xf, true);
    return v + __int_as_float(r);
}
// allreduce over each 16-lane row via rotate-by-1/2/4/8 (VALU pipe, no LDS)
__device__ __forceinline__ float row_allreduce(float v) {
    v = ror_add<0x121>(v);   // row_ror:1
    v = ror_add<0x122>(v);   // row_ror:2
    v = ror_add<0x124>(v);   // row_ror:4
    v = ror_add<0x128>(v);   // row_ror:8
    return v;
}

// ---------------------------------------------------------------------------
// K0: fold Wk with sent_q: wk_t[h][d] = sum_k Wk[d, h*64+k] * sent_q[h,k]
// (bk is softmax-shift-invariant; Wq/bq dead: token softmax is over a singleton)
// ---------------------------------------------------------------------------
__global__ void precompute_wk(const float* __restrict__ Wk,
                              const float* __restrict__ sq,
                              float* __restrict__ wk_t) {
    const int d = threadIdx.x;
    const int h = blockIdx.x;
    const float4* wrow = (const float4*)(Wk + (size_t)d * DD + h * DKK);
    const float4* sqv  = (const float4*)(sq + h * DKK);
    float acc = 0.f;
#pragma unroll
    for (int k = 0; k < DKK / 4; ++k) {
        float4 w = wrow[k], q = sqv[k];
        acc += w.x * q.x + w.y * q.y + w.z * q.z + w.w * q.w;
    }
    wk_t[h * DD + d] = acc;
}

// ---------------------------------------------------------------------------
// KS8: exp-weights with 8 tokens per wave, ALL x-loads issued up-front and
// independent (4KB/wave in flight -> fixes the 2-token duty-cycle stall that
// capped ks at ~2.8 TB/s). 2048 blocks x 256 thr (4 waves x 8 tokens).
// Dots -> DPP row allreduce -> head select -> xor16/32 -> exp.
// Store: all 64 lanes = 8 tokens x 8 heads, ONE contiguous 256B wave store.
// NO min-waves clause (R13 lesson: forcing it caps VGPR and spills).
// ---------------------------------------------------------------------------
__global__ __launch_bounds__(256)
void ks8_scores(const float* __restrict__ x, const int* __restrict__ mask,
                const float* __restrict__ wk_t, float* __restrict__ w)
{
    const int t    = threadIdx.x;
    const int wave = t >> 6;
    const int lane = t & 63;
    const int d0   = lane * 8;
    const int tok0 = blockIdx.x * 32 + wave * 8;

    // ---- all 16 x-loads + 2 mask loads issued before anything else ----
    const float* xp = x + (size_t)tok0 * DD + d0;
    float4 A[8], B[8];
#pragma unroll
    for (int j = 0; j < 8; ++j) {
        A[j] = *(const float4*)(xp + (size_t)j * DD);
        B[j] = *(const float4*)(xp + (size_t)j * DD + 4);
    }
    const int4 m03 = *(const int4*)(mask + tok0);
    const int4 m47 = *(const int4*)(mask + tok0 + 4);

    // wk fragments (L2-hot): 8 heads x 8 dims
    float4 wkA[HH], wkB[HH];
#pragma unroll
    for (int h = 0; h < HH; ++h) {
        wkA[h] = *(const float4*)(wk_t + h * DD + d0);
        wkB[h] = *(const float4*)(wk_t + h * DD + d0 + 4);
    }

    const int r = lane & 7;
    float e[8];
#pragma unroll
    for (int j = 0; j < 8; ++j) {
        float p[HH];
#pragma unroll
        for (int h = 0; h < HH; ++h) {
            p[h] = A[j].x * wkA[h].x + A[j].y * wkA[h].y
                 + A[j].z * wkA[h].z + A[j].w * wkA[h].w
                 + B[j].x * wkB[h].x + B[j].y * wkB[h].y
                 + B[j].z * wkB[h].z + B[j].w * wkB[h].w;
        }
#pragma unroll
        for (int h = 0; h < HH; ++h) p[h] = row_allreduce(p[h]);
        float v = p[0];
#pragma unroll
        for (int h = 1; h < HH; ++h) v = (r == h) ? p[h] : v;
        v += __shfl_xor(v, 16, 64);
        v += __shfl_xor(v, 32, 64);
        const int m = (j < 4) ? ((const int*)&m03)[j & 3] : ((const int*)&m47)[j & 3];
        e[j] = m ? __expf(v * 0.125f) : 0.f;
    }

    // lane = j*8 + h -> token tok0+j, head h: one contiguous 256B wave store
    const int g = lane >> 3;
    float eo = e[0];
#pragma unroll
    for (int j = 1; j < 8; ++j) eo = (g == j) ? e[j] : eo;
    w[(size_t)tok0 * HH + lane] = eo;
}

// ---------------------------------------------------------------------------
// KX2: xbar[sent][h][d] = sum_s w[s][h]*x[s][d] / sum_s w[s][h].
// Block = (sent, half of dims), 128 thr, thread owns a dim PAIR (float2
// loads, 8B/lane). w staged in 4KB LDS (broadcast reads); x 8-deep
// prefetched (LLC-hot after KS); per-head wsum redundant per thread.
// ---------------------------------------------------------------------------
__global__ __launch_bounds__(128)
void kx2_xbar(const float* __restrict__ x, const float* __restrict__ w,
              float* __restrict__ xbar)
{
    __shared__ float wl[SS][HH];   // 4 KB

    const int bid  = blockIdx.x;
    const int sent = bid >> 1, half = bid & 1;
    const int t    = threadIdx.x;

    // stage w[sent][s][h]: thread t loads row s=t (8 floats)
    {
        const float4* wp = (const float4*)(w + (size_t)sent * SS * HH);
        const float4 w0 = wp[t * 2];
        const float4 w1 = wp[t * 2 + 1];
        *(float4*)&wl[t][0] = w0;
        *(float4*)&wl[t][4] = w1;
    }
    __syncthreads();

    const int d = half * 256 + t * 2;
    const float* xp = x + (size_t)sent * SENT_STRIDE + d;

    float acc0[HH], acc1[HH], wsum[HH];
#pragma unroll
    for (int h = 0; h < HH; ++h) { acc0[h] = 0.f; acc1[h] = 0.f; wsum[h] = 0.f; }

    float2 xa[8], xb[8];
#pragma unroll
    for (int j = 0; j < 8; ++j) xa[j] = *(const float2*)(xp + (size_t)j * DD);

    for (int s0 = 0; s0 < SS; s0 += 16) {
#pragma unroll
        for (int j = 0; j < 8; ++j) xb[j] = *(const float2*)(xp + (size_t)(s0 + 8 + j) * DD);
#pragma unroll
        for (int j = 0; j < 8; ++j) {
            const float4 w0 = *(const float4*)&wl[s0 + j][0];
            const float4 w1 = *(const float4*)&wl[s0 + j][4];
            const float x0 = xa[j].x, x1 = xa[j].y;
            acc0[0] += w0.x * x0; acc0[1] += w0.y * x0; acc0[2] += w0.z * x0; acc0[3] += w0.w * x0;
            acc0[4] += w1.x * x0; acc0[5] += w1.y * x0; acc0[6] += w1.z * x0; acc0[7] += w1.w * x0;
            acc1[0] += w0.x * x1; acc1[1] += w0.y * x1; acc1[2] += w0.z * x1; acc1[3] += w0.w * x1;
            acc1[4] += w1.x * x1; acc1[5] += w1.y * x1; acc1[6] += w1.z * x1; acc1[7] += w1.w * x1;
            wsum[0] += w0.x; wsum[1] += w0.y; wsum[2] += w0.z; wsum[3] += w0.w;
            wsum[4] += w1.x; wsum[5] += w1.y; wsum[6] += w1.z; wsum[7] += w1.w;
        }
        if (s0 + 16 < SS) {
#pragma unroll
            for (int j = 0; j < 8; ++j) xa[j] = *(const float2*)(xp + (size_t)(s0 + 16 + j) * DD);
        }
#pragma unroll
        for (int j = 0; j < 8; ++j) {
            const float4 w0 = *(const float4*)&wl[s0 + 8 + j][0];
            const float4 w1 = *(const float4*)&wl[s0 + 8 + j][4];
            const float x0 = xb[j].x, x1 = xb[j].y;
            acc0[0] += w0.x * x0; acc0[1] += w0.y * x0; acc0[2] += w0.z * x0; acc0[3] += w0.w * x0;
            acc0[4] += w1.x * x0; acc0[5] += w1.y * x0; acc0[6] += w1.z * x0; acc0[7] += w1.w * x0;
            acc1[0] += w0.x * x1; acc1[1] += w0.y * x1; acc1[2] += w0.z * x1; acc1[3] += w0.w * x1;
            acc1[4] += w1.x * x1; acc1[5] += w1.y * x1; acc1[6] += w1.z * x1; acc1[7] += w1.w * x1;
            wsum[0] += w0.x; wsum[1] += w0.y; wsum[2] += w0.z; wsum[3] += w0.w;
            wsum[4] += w1.x; wsum[5] += w1.y; wsum[6] += w1.z; wsum[7] += w1.w;
        }
    }

    float* xbp = xbar + (size_t)sent * (HH * DD) + d;
#pragma unroll
    for (int h = 0; h < HH; ++h) {
        const float rr = 1.0f / wsum[h];
        float2 o; o.x = acc0[h] * rr; o.y = acc1[h] * rr;
        *(float2*)(xbp + h * DD) = o;
    }
}

// ---------------------------------------------------------------------------
// KZ/KY: 16x64-tile fp32 GEMM, register-prefetched across the barrier,
// 256 blocks (proven R8/R11).
//  KZ: A=xbar (am=4096, a_nb=512 head select), B=Wv, bias=bv -> z
//  KY: A=z    (am=512,  a_nb=0),               B=Wo, bias=bo -> y
// ---------------------------------------------------------------------------
__global__ __launch_bounds__(256)
void gemm_tile(const float* __restrict__ A, const int am_stride, const int a_nb_stride,
               const float* __restrict__ B, const float* __restrict__ bias,
               float* __restrict__ C)
{
    __shared__ float As[64][17];   // [k][m]
    __shared__ float Bs[64][68];   // [k][n]

    const int nb = blockIdx.x & 7, mb = blockIdx.x >> 3;
    const int t  = threadIdx.x;
    const int tr = t >> 4, tc = t & 15;

    const float* Ab = A + (size_t)(mb * 16) * am_stride + nb * a_nb_stride
                        + (size_t)tr * am_stride + tc * 4;
    const float* Bb = B + nb * 64 + (size_t)tr * DD + tc * 4;

    float4 ar = *(const float4*)(Ab);
    float4 br0 = *(const float4*)(Bb);
    float4 br1 = *(const float4*)(Bb + 16 * DD);
    float4 br2 = *(const float4*)(Bb + 32 * DD);
    float4 br3 = *(const float4*)(Bb + 48 * DD);

    float a0 = 0.f, a1 = 0.f, a2 = 0.f, a3 = 0.f;

    for (int k0 = 0; k0 < DD; k0 += 64) {
        As[tc * 4 + 0][tr] = ar.x;
        As[tc * 4 + 1][tr] = ar.y;
        As[tc * 4 + 2][tr] = ar.z;
        As[tc * 4 + 3][tr] = ar.w;
        *(float4*)&Bs[tr +  0][tc * 4] = br0;
        *(float4*)&Bs[tr + 16][tc * 4] = br1;
        *(float4*)&Bs[tr + 32][tc * 4] = br2;
        *(float4*)&Bs[tr + 48][tc * 4] = br3;
        __syncthreads();
        if (k0 + 64 < DD) {       // prefetch next K-tile; overlaps compute below
            ar  = *(const float4*)(Ab + k0 + 64);
            br0 = *(const float4*)(Bb + (size_t)(k0 + 64) * DD);
            br1 = *(const float4*)(Bb + (size_t)(k0 + 80) * DD);
            br2 = *(const float4*)(Bb + (size_t)(k0 + 96) * DD);
            br3 = *(const float4*)(Bb + (size_t)(k0 + 112) * DD);
        }
#pragma unroll
        for (int kk = 0; kk < 64; ++kk) {
            const float av = As[kk][tr];
            const float4 bv4 = *(const float4*)&Bs[kk][tc * 4];
            a0 += av * bv4.x; a1 += av * bv4.y; a2 += av * bv4.z; a3 += av * bv4.w;
        }
        __syncthreads();
    }

    const float4 bb = *(const float4*)(bias + nb * 64 + tc * 4);
    float4 o; o.x = a0 + bb.x; o.y = a1 + bb.y; o.z = a2 + bb.z; o.w = a3 + bb.w;
    *(float4*)(C + (size_t)(mb * 16 + tr) * DD + nb * 64 + tc * 4) = o;
}

// ---------------------------------------------------------------------------
// KB: broadcast y[sent] to all 128 token rows of out. 2048 blocks x 256 thr.
// Wave-stores are 1KB contiguous (proven-fast write pattern).
// ---------------------------------------------------------------------------
__global__ __launch_bounds__(256)
void kb_bcast(const float* __restrict__ y, float* __restrict__ outp)
{
    const int sent = blockIdx.x >> 2, q = blockIdx.x & 3;
    const int c4 = threadIdx.x & 127;       // float4 column 0..127
    const int rr = threadIdx.x >> 7;        // 0..1
    const float4 yv = *(const float4*)(y + (size_t)sent * DD + c4 * 4);
    float* w0 = outp + (size_t)sent * SENT_STRIDE + (size_t)(q * 32 + rr) * DD + c4 * 4;
#pragma unroll
    for (int i = 0; i < 16; ++i)
        *(float4*)(w0 + (size_t)(i * 2) * DD) = yv;
}

extern "C" void kernel_launch(void* const* d_in, const int* in_sizes, int n_in,
                              void* d_out, int out_size, void* d_ws, size_t ws_size,
                              hipStream_t stream) {
    const float* x    = (const float*)d_in[0];
    const int*   mask = (const int*)  d_in[1];
    // d_in[2]=Wq, d_in[3]=bq dead (token softmax over singleton); d_in[5]=bk shift-invariant
    const float* Wk   = (const float*)d_in[4];
    const float* Wv   = (const float*)d_in[6];
    const float* bv   = (const float*)d_in[7];
    const float* sq   = (const float*)d_in[8];
    const float* Wo   = (const float*)d_in[9];
    const float* bo   = (const float*)d_in[10];
    float* out = (float*)d_out;
    float* ws  = (float*)d_ws;

    float* wk_t = ws + WK_OFF;
    float* w    = ws + W_OFF;
    float* xbar = ws + XB_OFF;
    float* z    = ws + Z_OFF;    // aliases w (w dead after kx2)
    float* y    = ws + YY_OFF;

    precompute_wk<<<HH, DD, 0, stream>>>(Wk, sq, wk_t);
    ks8_scores<<<NTOK / 32, 256, 0, stream>>>(x, mask, wk_t, w);
    kx2_xbar<<<NSENT * 2, 128, 0, stream>>>(x, w, xbar);
    gemm_tile<<<256, 256, 0, stream>>>(xbar, HH * DD, DD, Wv, bv, z);
    gemm_tile<<<256, 256, 0, stream>>>(z, DD, 0, Wo, bo, y);
    kb_bcast<<<NSENT * 4, 256, 0, stream>>>(y, out);
}